// Round 3
// baseline (131.072 us; speedup 1.0000x reference)
//
#include <hip/hip_runtime.h>
#include <math.h>

// HOG-3D: central-difference gradients -> (theta,phi) soft-binned histogram scatter.
// Output (1,8,8,78,78,78) fp32 = 121.5 MB.
//
// R2: the np reference is a faithful FLOAT32 chain (evidence: f64 chain in R1
// still flipped bin-boundary voxels). The reference is discontinuous at integer
// t_raw/p_raw, so we must match its f32 bits at the binning decision:
//  - every arithmetic op done in f32, same order as numpy (IEEE ops are
//    correctly rounded -> bitwise match given same operands/order)
//  - atan2f/acosf computed as f64 libm rounded to f32 = correctly-rounded f32
//    (matches glibc's near-CR float32 routines except on ~never inputs)
//  - fp contract OFF so mag2 isn't FMA-contracted (would differ from numpy)
//
// Each thread owns one (z,y,x) column across all 64 (t,p) planes and writes
// every plane (deposit or zero) -> no memset pass, no atomics, coalesced.

#define DVOL 64
#define S 78              // 64 + 2*8 - 2
#define S3 (S * S * S)    // 474552

__device__ __forceinline__ float ldx(const float* __restrict__ x, int z, int y, int xx) {
    if ((unsigned)z < (unsigned)DVOL && (unsigned)y < (unsigned)DVOL && (unsigned)xx < (unsigned)DVOL)
        return x[(z * DVOL + y) * DVOL + xx];
    return 0.0f;
}

__global__ void __launch_bounds__(256) hog_scatter(const float* __restrict__ x,
                                                   float* __restrict__ out) {
#pragma clang fp contract(off)
    int idx = blockIdx.x * blockDim.x + threadIdx.x;
    if (idx >= S3) return;
    int ox = idx % S;
    int r  = idx / S;
    int oy = r % S;
    int oz = r / S;
    int ix = ox - 7, iy = oy - 7, iz = oz - 7;

    // f32 central differences (IEEE subtract == numpy bitwise)
    float gz = ldx(x, iz + 1, iy, ix) - ldx(x, iz - 1, iy, ix);
    float gy = ldx(x, iz, iy + 1, ix) - ldx(x, iz, iy - 1, ix);
    float gx = ldx(x, iz, iy, ix + 1) - ldx(x, iz, iy, ix - 1);

    // np.sum(out*out, axis=0) order: ((c0^2 + c1^2) + c2^2), all f32, no FMA
    float mag2 = (gz * gz + gy * gy) + gx * gx;
    float mag  = sqrtf(mag2);                      // IEEE sqrt

    float wv0 = 0.0f, wv1 = 0.0f, wv2 = 0.0f;
    int b0 = -1, b1 = -1, b2 = -1;

    if (mag != 0.0f) {
        // correctly-rounded f32 atan2/acos via f64 libm
        float theta = (float)atan2((double)gy, (double)gx);
        const float EPS32 = 2.220446049250313e-16f;   // 2^-52, exact in f32
        float denom = mag + EPS32;                    // f32 add (== numpy)
        float ratio = gz / denom;                     // IEEE f32 divide
        float phi = (float)acos((double)ratio);

        const float PI32 = 3.14159274101257324f;      // (float)math.pi
        float t_raw = theta / PI32 * 8.0f;            // f32 div, then *8 (exact)
        float p_raw = phi   / PI32 * 8.0f;

        float t_frac = t_raw - truncf(t_raw);         // torch.frac (signed), exact
        float p_frac = p_raw - truncf(p_raw);

        // numpy floored-mod, pow2 divisor -> two's-complement AND
        int i0 = ((int)floorf(t_raw)) & 7;
        int i1 = ((int)ceilf (t_raw)) & 7;
        int i2 = ((int)floorf(p_raw)) & 7;
        int i3 = ((int)ceilf (p_raw)) & 7;

        float f0 = fabsf(t_frac), f1 = fabsf(1.0f - t_frac);
        float f2 = fabsf(p_frac), f3 = fabsf(1.0f - p_frac);
        wv0 = (f0 * f2) * mag;   // -> (i0, i2)
        wv1 = (f0 * f3) * mag;   // -> (i0, i3)
        wv2 = (f1 * f2) * mag;   // -> (i1, i2)

        b0 = i0 * 8 + i2; b1 = i0 * 8 + i3; b2 = i1 * 8 + i2;
        // merge colliding deposits in the reference add order ((w0+w1)+w2)
        if (b1 == b0) { wv0 = wv0 + wv1; b1 = -1; }
        if (b2 == b0) { wv0 = wv0 + wv2; b2 = -1; }
        // (b2==b1 with b1!=b0 is impossible: would require i1==i0 && i3==i2)
    }

    // write the full 64-plane column: deposit or zero; coalesced per plane
    #pragma unroll
    for (int p = 0; p < 64; ++p) {
        float v = 0.0f;
        if (p == b0) v = wv0;
        if (p == b1) v = wv1;
        if (p == b2) v = wv2;
        out[(size_t)p * S3 + idx] = v;
    }
}

extern "C" void kernel_launch(void* const* d_in, const int* in_sizes, int n_in,
                              void* d_out, int out_size, void* d_ws, size_t ws_size,
                              hipStream_t stream) {
    const float* x = (const float*)d_in[0];   // (64,64,64) fp32
    // d_in[1] (sobel weight) is a fixed constant per the reference -- folded in.
    float* out = (float*)d_out;

    const int threads = 256;
    const int blocks = (S3 + threads - 1) / threads;
    hog_scatter<<<blocks, threads, 0, stream>>>(x, out);
}